// Round 13
// baseline (932.002 us; speedup 1.0000x reference)
//
#include <hip/hip_runtime.h>

#define NN 12288
#define OUTF 64
#define ALPHA 0.2f
#define C1 6.0f
#define KSP 8
#define KRANGE (NN / KSP)    /* 1536 per block */
#define PAIRS 12             /* 24 k64-slabs = 12 pairs */

typedef unsigned short u16;
typedef unsigned int u32;
typedef unsigned long long u64;
typedef _Float16 half8 __attribute__((ext_vector_type(8)));
typedef float floatx4 __attribute__((ext_vector_type(4)));
typedef int intx4 __attribute__((ext_vector_type(4)));

union H16 { u16 u; _Float16 h; };
__device__ __forceinline__ u16 f2h(float f) { H16 c; c.h = (_Float16)f; return c.u; }

// async global->LDS DMA, 16 B per lane; lds dest = wave-uniform base + lane*16
__device__ __forceinline__ void g2l16(const void* g, void* l) {
  __builtin_amdgcn_global_load_lds(
      (const __attribute__((address_space(1))) void*)g,
      (__attribute__((address_space(3))) void*)l, 16, 0, 0);
}

// ---------------- K1: h = X@W, per-node scalars, Btf in MFMA-fragment order --------------
// 192 blocks x 64 nodes. Btf chunk (k32, n): 64 lanes x 16 B contiguous; lane element j' =
// B_row(n*16+lane%16), source node k32*32 + (lane/16)*8 + j'.  B_row r: r<64: e1*h[r];
// r==64: e1; 65..79: 0; 80..143: e2*h[r-80]; r==144: e2; 145..159: 0.
__global__ __launch_bounds__(256) void k1_prep(
    const float* __restrict__ inp, const float* __restrict__ W, const float* __restrict__ a,
    u16* __restrict__ e1h, u16* __restrict__ thh,
    float* __restrict__ f1g, float* __restrict__ f2g, u16* __restrict__ Btf)
{
  __shared__ float Wl[128 * 64];               // 32 KB
  __shared__ float hsm[64][65];                // 16.6 KB
  __shared__ float e1sm[64], e2sm[64];
  const int tid = threadIdx.x, wave = tid >> 6, lane = tid & 63;
  const int b = blockIdx.x;                    // 64-node group
  for (int t = tid; t < 2048; t += 256)
    ((float4*)Wl)[t] = ((const float4*)W)[t];
  const float a1l = a[lane], a2l = a[OUTF + lane];
  __syncthreads();
  for (int jl = 0; jl < 16; ++jl) {
    const int jn = wave * 16 + jl;             // local node 0..63
    const int j = b * 64 + jn;
    const float4* xp = (const float4*)(inp + (size_t)j * 128);
    float h = 0.f;
#pragma unroll
    for (int c4 = 0; c4 < 32; ++c4) {
      float4 v = xp[c4];
      const int k = c4 * 4;
      h += v.x * Wl[k * 64 + lane] + v.y * Wl[(k + 1) * 64 + lane]
         + v.z * Wl[(k + 2) * 64 + lane] + v.w * Wl[(k + 3) * 64 + lane];
    }
    float p1 = h * a1l, p2 = h * a2l;
#pragma unroll
    for (int off = 32; off > 0; off >>= 1) { p1 += __shfl_xor(p1, off); p2 += __shfl_xor(p2, off); }
    hsm[jn][lane] = h;
    if (lane == 0) {
      const float s1 = p1, s2 = p2;
      const float e1 = expf(s2 - C1), e2 = expf(ALPHA * s2);
      e1sm[jn] = e1; e2sm[jn] = e2;
      e1h[j] = f2h(e1);
      thh[j] = f2h(expf(-s1 - C1));            // pos branch iff e1h[j] > thh[i] (u16-monotone)
      f1g[j] = expf(s1 + C1);
      f2g[j] = expf(ALPHA * s1);
    }
  }
  __syncthreads();
  // phase B: block covers 2 full k32 slabs (k32 = b*2+s). 1280 uint4 items, 5/thread.
  for (int cc = tid; cc < 1280; cc += 256) {
    const int s = cc / 640, rem = cc - s * 640;
    const int n = rem >> 6, l = rem & 63;
    const int r = n * 16 + (l & 15);
    const int jb = s * 32 + (l >> 4) * 8;      // local node base for this item's 8 elements
    u32 wpk[4];
#pragma unroll
    for (int p = 0; p < 4; ++p) {
      u16 hh[2];
#pragma unroll
      for (int q2 = 0; q2 < 2; ++q2) {
        const int jj = jb + p * 2 + q2;
        float v;
        if (r < 64)        v = e1sm[jj] * hsm[jj][r];
        else if (r == 64)  v = e1sm[jj];
        else if (r < 80)   v = 0.f;
        else if (r < 144)  v = e2sm[jj] * hsm[jj][r - 80];
        else if (r == 144) v = e2sm[jj];
        else               v = 0.f;
        hh[q2] = f2h(v);
      }
      wpk[p] = (u32)hh[0] | ((u32)hh[1] << 16);
    }
    ((uint4*)Btf)[(size_t)((b * 2 + s) * 10 + n) * 64 + l] = make_uint4(wpk[0], wpk[1], wpk[2], wpk[3]);
  }
}

// ---- k2 helper macros (all register-array indices compile-time constant) ----------------

// load one pair (2 slabs) of this wave's 32 adj rows into raw regs + e1h vectors
#define LOAD_PAIR(pairIdx)                                                                 \
  {                                                                                        \
    _Pragma("unroll")                                                                      \
    for (int s = 0; s < 2; ++s) {                                                          \
      const int koff = (pairIdx) * 128 + s * 64;                                           \
      _Pragma("unroll")                                                                    \
      for (int p = 0; p < 4; ++p) {                                                        \
        raw[s][p][0] = __builtin_nontemporal_load((const intx4*)(aB + (size_t)p * 8 * NN + koff));     \
        raw[s][p][1] = __builtin_nontemporal_load((const intx4*)(aB + (size_t)p * 8 * NN + koff + 4)); \
      }                                                                                    \
      evr[s] = *(const uint4*)(eB + koff);                                                 \
    }                                                                                      \
  }

// pack raw -> per-lane mask bytes: PK1/PK2[s] = u32, byte p = mask bits for
// row wave*32+p*8+prow8, k-bits pcol*8..+8 of slab s
#define PACK_PAIR(PK1, PK2)                                                                \
  {                                                                                        \
    _Pragma("unroll")                                                                      \
    for (int s = 0; s < 2; ++s) {                                                          \
      u32 ev8[8] = {evr[s].x & 0xFFFFu, evr[s].x >> 16, evr[s].y & 0xFFFFu, evr[s].y >> 16,\
                    evr[s].z & 0xFFFFu, evr[s].z >> 16, evr[s].w & 0xFFFFu, evr[s].w >> 16};\
      u32 o1 = 0, o2 = 0;                                                                  \
      _Pragma("unroll")                                                                    \
      for (int p = 0; p < 4; ++p) {                                                        \
        const int av[8] = {raw[s][p][0].x, raw[s][p][0].y, raw[s][p][0].z, raw[s][p][0].w, \
                           raw[s][p][1].x, raw[s][p][1].y, raw[s][p][1].z, raw[s][p][1].w};\
        u32 b1 = 0, b2 = 0;                                                                \
        _Pragma("unroll")                                                                  \
        for (int e = 0; e < 8; ++e) {                                                      \
          const bool nbr = av[e] > 0;                                                      \
          const bool up = ev8[e] > (u32)thu[p];                                            \
          b1 |= (u32)(nbr && up) << e;                                                     \
          b2 |= (u32)(nbr && !up) << e;                                                    \
        }                                                                                  \
        o1 |= b1 << (8 * p);                                                               \
        o2 |= b2 << (8 * p);                                                               \
      }                                                                                    \
      PK1[s] = o1; PK2[s] = o2;                                                            \
    }                                                                                      \
  }

// DMA a 40-KB B pair into ring buffers [pb*2, pb*2+1]
#define DMA_PAIR(pb, pairIdx)                                                              \
  {                                                                                        \
    const char* src = (const char*)(Btf + ((size_t)(k0 >> 5) + (size_t)(pairIdx) * 4) * 5120); \
    _Pragma("unroll")                                                                      \
    for (int i = 0; i < 10; ++i)                                                           \
      g2l16(src + i * 4096 + tid * 16, (char*)&sB[(pb) * 2][0] + i * 4096 + wave * 1024);  \
  }

// compute both slabs of the pair in ring half pb, masks via in-wave shuffle
#define COMPUTE_PAIR(pb, PK1, PK2)                                                         \
  {                                                                                        \
    _Pragma("unroll")                                                                      \
    for (int s = 0; s < 2; ++s) {                                                          \
      _Pragma("unroll")                                                                    \
      for (int h = 0; h < 2; ++h) {                                                        \
        const int sl = ((lr & 7) << 3) | (h * 4 + quad);                                   \
        const u32 v1 = (u32)__shfl((int)PK1[s], sl);                                       \
        const u32 v2 = (u32)__shfl((int)PK2[s], sl);                                       \
        union { half8 v; u16 s[8]; } A1[2], A2[2];                                         \
        _Pragma("unroll")                                                                  \
        for (int t = 0; t < 2; ++t) {                                                      \
          const u32 sh2 = 8u * (u32)(t * 2 + (lr >> 3));                                   \
          const u32 m1 = (v1 >> sh2) & 0xFFu;                                              \
          const u32 m2 = (v2 >> sh2) & 0xFFu;                                              \
          _Pragma("unroll")                                                                \
          for (int e = 0; e < 8; ++e) {                                                    \
            A1[t].s[e] = ((m1 >> e) & 1u) ? (u16)0x3C00 : (u16)0;                          \
            A2[t].s[e] = ((m2 >> e) & 1u) ? (u16)0x3C00 : (u16)0;                          \
          }                                                                                \
        }                                                                                  \
        const u16* bp = &sB[(pb) * 2 + s][h * 5120];                                       \
        _Pragma("unroll")                                                                  \
        for (int n = 0; n < 10; ++n) {                                                     \
          half8 Bv = *(const half8*)(bp + (n * 64 + lane) * 8);                            \
          acc[0][n] = __builtin_amdgcn_mfma_f32_16x16x32_f16(n < 5 ? A1[0].v : A2[0].v, Bv,\
                                                             acc[0][n], 0, 0, 0);          \
          acc[1][n] = __builtin_amdgcn_mfma_f32_16x16x32_f16(n < 5 ? A1[1].v : A2[1].v, Bv,\
                                                             acc[1][n], 0, 0, 0);          \
        }                                                                                  \
      }                                                                                    \
    }                                                                                      \
  }

// ---------------- K2: FUSED adj-pack + paired-LDS bit-masked dual GEMM -------------------
// 768 blocks = 96 mpos x 8 ksplit. Barrier per PAIR of slabs (12 total, halving vmcnt(0)
// drains); masks are wave-private (packed in registers, A-frag bytes pulled via __shfl) so
// the barrier protects only the 80-KB B ring. adj prefetched one pair ahead.
__global__ __launch_bounds__(256, 2) void k2_main(
    const int* __restrict__ adj, const u16* __restrict__ e1h, const u16* __restrict__ thh,
    const u16* __restrict__ Btf, float* __restrict__ part)
{
  __shared__ u16 sB[4][10240];                 // 80 KB: two 40-KB pair buffers
  const int tid = threadIdx.x;
  const int wave = tid >> 6, lane = tid & 63;
  const int quad = lane >> 4, lr = lane & 15;
  const int mpos = (int)blockIdx.x >> 3;
  const int ks = (int)blockIdx.x & 7;
  const int mbase = mpos * 128;
  const int k0 = ks * KRANGE;

  // wave-private pack role: lane = prow8*8+pcol; rows wave*32 + p*8 + prow8, k-bytes pcol
  const int prow8 = lane >> 3, pcol = lane & 7;
  u16 thu[4];
#pragma unroll
  for (int p = 0; p < 4; ++p) thu[p] = thh[mbase + wave * 32 + p * 8 + prow8];
  const int* aB = adj + (size_t)(mbase + wave * 32 + prow8) * NN + k0 + pcol * 8;
  const u16* eB = e1h + k0 + pcol * 8;

  floatx4 acc[2][10];
#pragma unroll
  for (int t = 0; t < 2; ++t)
#pragma unroll
    for (int n = 0; n < 10; ++n) acc[t][n] = (floatx4){0.f, 0.f, 0.f, 0.f};

  intx4 raw[2][4][2];                          // one pair of raw adj (reused each pair)
  uint4 evr[2];
  u32 pk1a[2], pk2a[2], pk1b[2], pk2b[2];      // packed masks: pair-parity a/b

  // ---- prologue: B pair 0 via DMA; adj pair 0 -> pack a; adj pair 1 -> raw ----
  DMA_PAIR(0, 0)
  LOAD_PAIR(0)
  PACK_PAIR(pk1a, pk2a)
  LOAD_PAIR(1)

  for (int cp = 0; cp < PAIRS; cp += 2) {
    // ---- even pair cp: ring half 0; pack pair cp+1 from raw; refill raw <- cp+2 ----
    __syncthreads();
    if (cp + 1 < PAIRS) {
      DMA_PAIR(1, cp + 1)
      PACK_PAIR(pk1b, pk2b)
    }
    if (cp + 2 < PAIRS) LOAD_PAIR(cp + 2)
    COMPUTE_PAIR(0, pk1a, pk2a)
    // ---- odd pair cp+1: ring half 1; pack pair cp+2; refill raw <- cp+3 ----
    __syncthreads();
    if (cp + 2 < PAIRS) {
      DMA_PAIR(0, cp + 2)
      PACK_PAIR(pk1a, pk2a)
    }
    if (cp + 3 < PAIRS) LOAD_PAIR(cp + 3)
    COMPUTE_PAIR(1, pk1b, pk2b)
  }

  // partial store. C/D: col=lane&15, row=quad*4+reg; tile t -> local rows wave*32+t*16+..
  const int ks96 = ks * 96 + mpos;
#pragma unroll
  for (int t = 0; t < 2; ++t) {
    float* pp = part + ((size_t)ks96 * 128 + wave * 32 + t * 16 + quad * 4) * 132;
#pragma unroll
    for (int r = 0; r < 4; ++r) {
#pragma unroll
      for (int n = 0; n < 4; ++n)
        pp[r * 132 + n * 16 + lr] = acc[t][n][r];
#pragma unroll
      for (int n = 5; n < 9; ++n)
        pp[r * 132 + 64 + (n - 5) * 16 + lr] = acc[t][n][r];
      if (lr == 0) {
        pp[r * 132 + 128] = acc[t][4][r];      // den+ (group 4, col 0)
        pp[r * 132 + 129] = acc[t][9][r];      // den- (group 9, col 0)
      }
    }
  }
}

// ---------------- K3: reduce 8 k-split partials, scale, divide, ELU ----------------------
__global__ __launch_bounds__(256) void k3_final(
    const float* __restrict__ part, const float* __restrict__ f1g,
    const float* __restrict__ f2g, float* __restrict__ out)
{
  const int gid = blockIdx.x * 256 + threadIdx.x;
  const int row = gid >> 6, col = gid & 63;
  const int mpos = row >> 7, r = row & 127;
  float n1 = 0.f, n2 = 0.f, d1 = 0.f, d2 = 0.f;
#pragma unroll
  for (int ks = 0; ks < KSP; ++ks) {
    const float* p = part + ((size_t)(ks * 96 + mpos) * 128 + r) * 132;
    n1 += p[col]; n2 += p[64 + col]; d1 += p[128]; d2 += p[129];
  }
  const float f1 = f1g[row], f2 = f2g[row];
  const float num = f1 * n1 + f2 * n2;
  const float den = fmaxf(f1 * d1 + f2 * d2, 1e-30f);
  const float x = num / den;
  out[gid] = x > 0.f ? x : (expf(x) - 1.f);
}

extern "C" void kernel_launch(void* const* d_in, const int* in_sizes, int n_in,
                              void* d_out, int out_size, void* d_ws, size_t ws_size,
                              hipStream_t stream) {
  const float* inp = (const float*)d_in[0];
  const int* adj = (const int*)d_in[1];
  const float* W = (const float*)d_in[2];
  const float* a = (const float*)d_in[3];

  // ws: Btf 3,932,160 | part 51,904,512 | e1h 24,576 | thh 24,576 | f1g 49,152 | f2g 49,152
  char* ws = (char*)d_ws;
  u16* Btf = (u16*)ws;
  float* part = (float*)(ws + 3932160);
  char* tail = ws + 3932160 + 51904512;
  u16* e1h = (u16*)tail;
  u16* thh = e1h + NN;
  float* f1g = (float*)(thh + NN);
  float* f2g = f1g + NN;

  k1_prep<<<192, 256, 0, stream>>>(inp, W, a, e1h, thh, f1g, f2g, Btf);
  k2_main<<<768, 256, 0, stream>>>(adj, e1h, thh, Btf, part);
  k3_final<<<NN * OUTF / 256, 256, 0, stream>>>(part, f1g, f2g, (float*)d_out);
}

// Round 14
// 877.203 us; speedup vs baseline: 1.0625x; 1.0625x over previous
//
#include <hip/hip_runtime.h>

#define NN 12288
#define OUTF 64
#define ALPHA 0.2f
#define C1 6.0f
#define KSP 8
#define KRANGE (NN / KSP)    /* 1536 per block */
#define ITERS (KRANGE / 64)  /* 24 */

typedef unsigned short u16;
typedef unsigned int u32;
typedef unsigned long long u64;
typedef _Float16 half8 __attribute__((ext_vector_type(8)));
typedef float floatx4 __attribute__((ext_vector_type(4)));
typedef int intx4 __attribute__((ext_vector_type(4)));

union H16 { u16 u; _Float16 h; };
__device__ __forceinline__ u16 f2h(float f) { H16 c; c.h = (_Float16)f; return c.u; }

// async global->LDS DMA, 16 B per lane; lds dest = wave-uniform base + lane*16
__device__ __forceinline__ void g2l16(const void* g, void* l) {
  __builtin_amdgcn_global_load_lds(
      (const __attribute__((address_space(1))) void*)g,
      (__attribute__((address_space(3))) void*)l, 16, 0, 0);
}

// ---------------- K1 (R12-proven, 192 blocks x 64 nodes): h = X@W, scalars, Btf ----------
// Btf chunk (k32, n): 64 lanes x 16 B contiguous; lane element j' = B_row(n*16+lane%16),
// source node k32*32 + (lane/16)*8 + j'.  B_row r: r<64: e1*h[r]; r==64: e1; 65..79: 0;
// 80..143: e2*h[r-80]; r==144: e2; 145..159: 0.   e1=exp(s2-C1), e2=exp(a*s2).
__global__ __launch_bounds__(256) void k1_prep(
    const float* __restrict__ inp, const float* __restrict__ W, const float* __restrict__ a,
    u16* __restrict__ e1h, u16* __restrict__ thh,
    float* __restrict__ f1g, float* __restrict__ f2g, u16* __restrict__ Btf)
{
  __shared__ float Wl[128 * 64];               // 32 KB
  __shared__ float hsm[64][65];                // 16.6 KB
  __shared__ float e1sm[64], e2sm[64];
  const int tid = threadIdx.x, wave = tid >> 6, lane = tid & 63;
  const int b = blockIdx.x;                    // 64-node group
  for (int t = tid; t < 2048; t += 256)
    ((float4*)Wl)[t] = ((const float4*)W)[t];
  const float a1l = a[lane], a2l = a[OUTF + lane];
  __syncthreads();
  for (int jl = 0; jl < 16; ++jl) {
    const int jn = wave * 16 + jl;             // local node 0..63
    const int j = b * 64 + jn;
    const float4* xp = (const float4*)(inp + (size_t)j * 128);
    float h = 0.f;
#pragma unroll
    for (int c4 = 0; c4 < 32; ++c4) {
      float4 v = xp[c4];
      const int k = c4 * 4;
      h += v.x * Wl[k * 64 + lane] + v.y * Wl[(k + 1) * 64 + lane]
         + v.z * Wl[(k + 2) * 64 + lane] + v.w * Wl[(k + 3) * 64 + lane];
    }
    float p1 = h * a1l, p2 = h * a2l;
#pragma unroll
    for (int off = 32; off > 0; off >>= 1) { p1 += __shfl_xor(p1, off); p2 += __shfl_xor(p2, off); }
    hsm[jn][lane] = h;
    if (lane == 0) {
      const float s1 = p1, s2 = p2;
      const float e1 = expf(s2 - C1), e2 = expf(ALPHA * s2);
      e1sm[jn] = e1; e2sm[jn] = e2;
      e1h[j] = f2h(e1);
      thh[j] = f2h(expf(-s1 - C1));            // pos branch iff e1h[j] > thh[i] (u16-monotone)
      f1g[j] = expf(s1 + C1);
      f2g[j] = expf(ALPHA * s1);
    }
  }
  __syncthreads();
  // phase B: block covers 2 full k32 slabs (k32 = b*2+s). 1280 uint4 items, 5/thread.
  for (int cc = tid; cc < 1280; cc += 256) {
    const int s = cc / 640, rem = cc - s * 640;
    const int n = rem >> 6, l = rem & 63;
    const int r = n * 16 + (l & 15);
    const int jb = s * 32 + (l >> 4) * 8;      // local node base for this item's 8 elements
    u32 wpk[4];
#pragma unroll
    for (int p = 0; p < 4; ++p) {
      u16 hh[2];
#pragma unroll
      for (int q2 = 0; q2 < 2; ++q2) {
        const int jj = jb + p * 2 + q2;
        float v;
        if (r < 64)        v = e1sm[jj] * hsm[jj][r];
        else if (r == 64)  v = e1sm[jj];
        else if (r < 80)   v = 0.f;
        else if (r < 144)  v = e2sm[jj] * hsm[jj][r - 80];
        else if (r == 144) v = e2sm[jj];
        else               v = 0.f;
        hh[q2] = f2h(v);
      }
      wpk[p] = (u32)hh[0] | ((u32)hh[1] << 16);
    }
    ((uint4*)Btf)[(size_t)((b * 2 + s) * 10 + n) * 64 + l] = make_uint4(wpk[0], wpk[1], wpk[2], wpk[3]);
  }
}

// ---------------- K2 (R10-proven winner, verbatim): FUSED adj-pack + LDS-staged GEMM -----
// 768 blocks = 96 mpos x 8 ksplit. Per k64 iter: DMA next 20-KB B-slab (global_load_lds),
// stream next 32-KB adj tile (nontemporal, read once grid-wide), pack branch-resolved mask
// bytes to double-buffered LDS, MFMA on current slab. One barrier per iter.
__global__ __launch_bounds__(256, 3) void k2_main(
    const int* __restrict__ adj, const u16* __restrict__ e1h, const u16* __restrict__ thh,
    const u16* __restrict__ Btf, float* __restrict__ part)
{
  __shared__ u16 sB[2][10240];                 // 40 KB B slabs
  __shared__ u64 m1s[2][128];                  // 2 KB pos-branch masks
  __shared__ u64 m2s[2][128];                  // 2 KB neg-branch masks
  const int tid = threadIdx.x;
  const int wave = tid >> 6, lane = tid & 63;
  const int quad = lane >> 4, lr = lane & 15;
  const int mpos = (int)blockIdx.x >> 3;
  const int ks = (int)blockIdx.x & 7;
  const int mbase = mpos * 128;
  const int k0 = ks * KRANGE;

  // pack role: rows prow+32p (p=0..3), cols pcol*8..+8 of each k64 slab
  const int prow = tid >> 3, pcol = tid & 7;
  u16 thu[4];
#pragma unroll
  for (int p = 0; p < 4; ++p) thu[p] = thh[mbase + p * 32 + prow];
  const int* aB = adj + (size_t)(mbase + prow) * NN + k0 + pcol * 8;
  const u16* eB = e1h + k0 + pcol * 8;

  floatx4 acc[2][10];
#pragma unroll
  for (int t = 0; t < 2; ++t)
#pragma unroll
    for (int n = 0; n < 10; ++n) acc[t][n] = (floatx4){0.f, 0.f, 0.f, 0.f};

  intx4 aj[4][2];
  uint4 evv;

  // ---- prologue: DMA slab 0, pack masks for slab 0 into buffer 0 ----
  {
    const char* src = (const char*)(Btf + ((size_t)(k0 >> 5)) * 5120);
#pragma unroll
    for (int i = 0; i < 5; ++i)
      g2l16(src + i * 4096 + tid * 16, (char*)&sB[0][0] + i * 4096 + wave * 1024);
#pragma unroll
    for (int p = 0; p < 4; ++p) {
      aj[p][0] = __builtin_nontemporal_load((const intx4*)(aB + (size_t)p * 32 * NN));
      aj[p][1] = __builtin_nontemporal_load((const intx4*)(aB + (size_t)p * 32 * NN + 4));
    }
    evv = *(const uint4*)eB;
    u32 ev8[8] = {evv.x & 0xFFFFu, evv.x >> 16, evv.y & 0xFFFFu, evv.y >> 16,
                  evv.z & 0xFFFFu, evv.z >> 16, evv.w & 0xFFFFu, evv.w >> 16};
#pragma unroll
    for (int p = 0; p < 4; ++p) {
      const int av[8] = {aj[p][0].x, aj[p][0].y, aj[p][0].z, aj[p][0].w,
                         aj[p][1].x, aj[p][1].y, aj[p][1].z, aj[p][1].w};
      u32 b1 = 0, b2 = 0;
#pragma unroll
      for (int e = 0; e < 8; ++e) {
        const bool nbr = av[e] > 0;
        const bool up = ev8[e] > (u32)thu[p];
        b1 |= (u32)(nbr && up) << e;
        b2 |= (u32)(nbr && !up) << e;
      }
      ((unsigned char*)&m1s[0][p * 32 + prow])[pcol] = (unsigned char)b1;
      ((unsigned char*)&m2s[0][p * 32 + prow])[pcol] = (unsigned char)b2;
    }
  }

  for (int it = 0; it < ITERS; ++it) {
    __syncthreads();                           // slab/masks [cur] ready (drains DMA + LDS)
    const int cur = it & 1, nxt = cur ^ 1;
    const bool more = (it + 1 < ITERS);
    if (more) {                                // stage slab it+1: B via DMA, adj into regs
      const char* src = (const char*)(Btf + ((size_t)(k0 >> 5) + (it + 1) * 2) * 5120);
#pragma unroll
      for (int i = 0; i < 5; ++i)
        g2l16(src + i * 4096 + tid * 16, (char*)&sB[nxt][0] + i * 4096 + wave * 1024);
      const int koff = (it + 1) * 64;
#pragma unroll
      for (int p = 0; p < 4; ++p) {
        aj[p][0] = __builtin_nontemporal_load((const intx4*)(aB + (size_t)p * 32 * NN + koff));
        aj[p][1] = __builtin_nontemporal_load((const intx4*)(aB + (size_t)p * 32 * NN + koff + 4));
      }
      evv = *(const uint4*)(eB + koff);
    }

    // ---- MFMA on [cur] ----
    u64 w1[2], w2[2];
    w1[0] = m1s[cur][wave * 32 + lr];      w1[1] = m1s[cur][wave * 32 + 16 + lr];
    w2[0] = m2s[cur][wave * 32 + lr];      w2[1] = m2s[cur][wave * 32 + 16 + lr];
#pragma unroll
    for (int h = 0; h < 2; ++h) {
      const u32 sh = (u32)(h * 32 + quad * 8);
      union { half8 v; u16 s[8]; } A1[2], A2[2];
      const u32 m1a = (u32)(w1[0] >> sh) & 0xFFu, m2a = (u32)(w2[0] >> sh) & 0xFFu;
      const u32 m1b = (u32)(w1[1] >> sh) & 0xFFu, m2b = (u32)(w2[1] >> sh) & 0xFFu;
#pragma unroll
      for (int e = 0; e < 8; ++e) {
        A1[0].s[e] = ((m1a >> e) & 1u) ? (u16)0x3C00 : (u16)0;
        A2[0].s[e] = ((m2a >> e) & 1u) ? (u16)0x3C00 : (u16)0;
        A1[1].s[e] = ((m1b >> e) & 1u) ? (u16)0x3C00 : (u16)0;
        A2[1].s[e] = ((m2b >> e) & 1u) ? (u16)0x3C00 : (u16)0;
      }
      const u16* bp = &sB[cur][h * 5120];
#pragma unroll
      for (int n = 0; n < 10; ++n) {
        half8 Bv = *(const half8*)(bp + (n * 64 + lane) * 8);
        acc[0][n] = __builtin_amdgcn_mfma_f32_16x16x32_f16(n < 5 ? A1[0].v : A2[0].v, Bv,
                                                           acc[0][n], 0, 0, 0);
        acc[1][n] = __builtin_amdgcn_mfma_f32_16x16x32_f16(n < 5 ? A1[1].v : A2[1].v, Bv,
                                                           acc[1][n], 0, 0, 0);
      }
    }

    // ---- pack masks for slab it+1 into [nxt] ----
    if (more) {
      u32 ev8[8] = {evv.x & 0xFFFFu, evv.x >> 16, evv.y & 0xFFFFu, evv.y >> 16,
                    evv.z & 0xFFFFu, evv.z >> 16, evv.w & 0xFFFFu, evv.w >> 16};
#pragma unroll
      for (int p = 0; p < 4; ++p) {
        const int av[8] = {aj[p][0].x, aj[p][0].y, aj[p][0].z, aj[p][0].w,
                           aj[p][1].x, aj[p][1].y, aj[p][1].z, aj[p][1].w};
        u32 b1 = 0, b2 = 0;
#pragma unroll
        for (int e = 0; e < 8; ++e) {
          const bool nbr = av[e] > 0;
          const bool up = ev8[e] > (u32)thu[p];
          b1 |= (u32)(nbr && up) << e;
          b2 |= (u32)(nbr && !up) << e;
        }
        ((unsigned char*)&m1s[nxt][p * 32 + prow])[pcol] = (unsigned char)b1;
        ((unsigned char*)&m2s[nxt][p * 32 + prow])[pcol] = (unsigned char)b2;
      }
    }
  }

  // partial store. C/D: col=lane&15, row=quad*4+reg; tile t -> local rows wave*32+t*16+..
  const int ks96 = ks * 96 + mpos;
#pragma unroll
  for (int t = 0; t < 2; ++t) {
    float* pp = part + ((size_t)ks96 * 128 + wave * 32 + t * 16 + quad * 4) * 132;
#pragma unroll
    for (int r = 0; r < 4; ++r) {
#pragma unroll
      for (int n = 0; n < 4; ++n)
        pp[r * 132 + n * 16 + lr] = acc[t][n][r];
#pragma unroll
      for (int n = 5; n < 9; ++n)
        pp[r * 132 + 64 + (n - 5) * 16 + lr] = acc[t][n][r];
      if (lr == 0) {
        pp[r * 132 + 128] = acc[t][4][r];      // den+ (group 4, col 0)
        pp[r * 132 + 129] = acc[t][9][r];      // den- (group 9, col 0)
      }
    }
  }
}

// ---------------- K3: reduce 8 k-split partials, scale, divide, ELU ----------------------
__global__ __launch_bounds__(256) void k3_final(
    const float* __restrict__ part, const float* __restrict__ f1g,
    const float* __restrict__ f2g, float* __restrict__ out)
{
  const int gid = blockIdx.x * 256 + threadIdx.x;
  const int row = gid >> 6, col = gid & 63;
  const int mpos = row >> 7, r = row & 127;
  float n1 = 0.f, n2 = 0.f, d1 = 0.f, d2 = 0.f;
#pragma unroll
  for (int ks = 0; ks < KSP; ++ks) {
    const float* p = part + ((size_t)(ks * 96 + mpos) * 128 + r) * 132;
    n1 += p[col]; n2 += p[64 + col]; d1 += p[128]; d2 += p[129];
  }
  const float f1 = f1g[row], f2 = f2g[row];
  const float num = f1 * n1 + f2 * n2;
  const float den = fmaxf(f1 * d1 + f2 * d2, 1e-30f);
  const float x = num / den;
  out[gid] = x > 0.f ? x : (expf(x) - 1.f);
}

extern "C" void kernel_launch(void* const* d_in, const int* in_sizes, int n_in,
                              void* d_out, int out_size, void* d_ws, size_t ws_size,
                              hipStream_t stream) {
  const float* inp = (const float*)d_in[0];
  const int* adj = (const int*)d_in[1];
  const float* W = (const float*)d_in[2];
  const float* a = (const float*)d_in[3];

  // ws: Btf 3,932,160 | part 51,904,512 | e1h 24,576 | thh 24,576 | f1g 49,152 | f2g 49,152
  char* ws = (char*)d_ws;
  u16* Btf = (u16*)ws;
  float* part = (float*)(ws + 3932160);
  char* tail = ws + 3932160 + 51904512;
  u16* e1h = (u16*)tail;
  u16* thh = e1h + NN;
  float* f1g = (float*)(thh + NN);
  float* f2g = f1g + NN;

  k1_prep<<<192, 256, 0, stream>>>(inp, W, a, e1h, thh, f1g, f2g, Btf);
  k2_main<<<768, 256, 0, stream>>>(adj, e1h, thh, Btf, part);
  k3_final<<<NN * OUTF / 256, 256, 0, stream>>>(part, f1g, f2g, (float*)d_out);
}

// Round 15
// 850.332 us; speedup vs baseline: 1.0960x; 1.0316x over previous
//
#include <hip/hip_runtime.h>

#define NN 12288
#define OUTF 64
#define ALPHA 0.2f
#define C1 6.0f
#define KSP 8
#define KRANGE (NN / KSP)    /* 1536 per block */
#define ITERS (KRANGE / 64)  /* 24 */

typedef unsigned short u16;
typedef unsigned int u32;
typedef unsigned long long u64;
typedef _Float16 half8 __attribute__((ext_vector_type(8)));
typedef float floatx4 __attribute__((ext_vector_type(4)));
typedef int intx4 __attribute__((ext_vector_type(4)));

union H16 { u16 u; _Float16 h; };
__device__ __forceinline__ u16 f2h(float f) { H16 c; c.h = (_Float16)f; return c.u; }

// async global->LDS DMA, 16 B per lane; lds dest = wave-uniform base + lane*16
__device__ __forceinline__ void g2l16(const void* g, void* l) {
  __builtin_amdgcn_global_load_lds(
      (const __attribute__((address_space(1))) void*)g,
      (__attribute__((address_space(3))) void*)l, 16, 0, 0);
}

// ---------------- K1 (R10-proven, 768 blocks x 16 nodes): h = X@W, scalars, Btf ----------
// Btf chunk (k32, n): 64 lanes x 16 B contiguous; lane element j' = B_row(n*16+lane%16),
// source node k32*32 + (lane/16)*8 + j'.  B_row r: r<64: e1*h[r]; r==64: e1; 65..79: 0;
// 80..143: e2*h[r-80]; r==144: e2; 145..159: 0.   e1=exp(s2-C1), e2=exp(a*s2).
__global__ __launch_bounds__(256) void k1_prep(
    const float* __restrict__ inp, const float* __restrict__ W, const float* __restrict__ a,
    u16* __restrict__ e1h, u16* __restrict__ thh,
    float* __restrict__ f1g, float* __restrict__ f2g, u16* __restrict__ Btf)
{
  __shared__ float Wl[128 * 64];
  __shared__ float hsm[16][66];
  __shared__ float e1sm[16], e2sm[16];
  const int tid = threadIdx.x;
  for (int t = tid; t < 128 * 64 / 4; t += 256)
    ((float4*)Wl)[t] = ((const float4*)W)[t];
  const int wave = tid >> 6, lane = tid & 63;
  const int k16 = blockIdx.x;                  // 16-node group
  const float a1l = a[lane], a2l = a[OUTF + lane];
  __syncthreads();
  for (int jl = 0; jl < 4; ++jl) {
    const int jn = wave * 4 + jl;              // local node 0..15
    const int j = k16 * 16 + jn;
    const float4* xp = (const float4*)(inp + (size_t)j * 128);
    float h = 0.f;
#pragma unroll
    for (int c4 = 0; c4 < 32; ++c4) {
      float4 v = xp[c4];
      const int k = c4 * 4;
      h += v.x * Wl[k * 64 + lane] + v.y * Wl[(k + 1) * 64 + lane]
         + v.z * Wl[(k + 2) * 64 + lane] + v.w * Wl[(k + 3) * 64 + lane];
    }
    float p1 = h * a1l, p2 = h * a2l;
#pragma unroll
    for (int off = 32; off > 0; off >>= 1) { p1 += __shfl_xor(p1, off); p2 += __shfl_xor(p2, off); }
    hsm[jn][lane] = h;
    if (lane == 0) {
      const float s1 = p1, s2 = p2;
      const float e1 = expf(s2 - C1), e2 = expf(ALPHA * s2);
      e1sm[jn] = e1; e2sm[jn] = e2;
      e1h[j] = f2h(e1);
      thh[j] = f2h(expf(-s1 - C1));            // pos branch iff e1h[j] > thh[i] (u16-monotone)
      f1g[j] = expf(s1 + C1);
      f2g[j] = expf(ALPHA * s1);
    }
  }
  __syncthreads();
  // phase B: this block covers half a k32 slab: lanes [hi, hi+32) of every n-chunk
  const int k32 = k16 >> 1, hi = (k16 & 1) * 32;
  for (int cc = tid; cc < 320; cc += 256) {
    const int n = cc >> 5, l32 = cc & 31;
    const int r = n * 16 + (l32 & 15);
    const int jb = (l32 >> 4) * 8;             // local node base for this lane's 8 elements
    u32 wpk[4];
#pragma unroll
    for (int p = 0; p < 4; ++p) {
      u16 hh[2];
#pragma unroll
      for (int q2 = 0; q2 < 2; ++q2) {
        const int jj = jb + p * 2 + q2;
        float v;
        if (r < 64)        v = e1sm[jj] * hsm[jj][r];
        else if (r == 64)  v = e1sm[jj];
        else if (r < 80)   v = 0.f;
        else if (r < 144)  v = e2sm[jj] * hsm[jj][r - 80];
        else if (r == 144) v = e2sm[jj];
        else               v = 0.f;
        hh[q2] = f2h(v);
      }
      wpk[p] = (u32)hh[0] | ((u32)hh[1] << 16);
    }
    ((uint4*)Btf)[(size_t)(k32 * 10 + n) * 64 + hi + l32] = make_uint4(wpk[0], wpk[1], wpk[2], wpk[3]);
  }
}

// ---------------- K2 (R10-proven winner, verbatim): FUSED adj-pack + LDS-staged GEMM -----
// 768 blocks = 96 mpos x 8 ksplit. Per k64 iter: DMA next 20-KB B-slab (global_load_lds),
// stream next 32-KB adj tile (nontemporal, read once grid-wide), pack branch-resolved mask
// bytes to double-buffered LDS, MFMA on current slab. One barrier per iter.
__global__ __launch_bounds__(256, 3) void k2_main(
    const int* __restrict__ adj, const u16* __restrict__ e1h, const u16* __restrict__ thh,
    const u16* __restrict__ Btf, float* __restrict__ part)
{
  __shared__ u16 sB[2][10240];                 // 40 KB B slabs
  __shared__ u64 m1s[2][128];                  // 2 KB pos-branch masks
  __shared__ u64 m2s[2][128];                  // 2 KB neg-branch masks
  const int tid = threadIdx.x;
  const int wave = tid >> 6, lane = tid & 63;
  const int quad = lane >> 4, lr = lane & 15;
  const int mpos = (int)blockIdx.x >> 3;
  const int ks = (int)blockIdx.x & 7;
  const int mbase = mpos * 128;
  const int k0 = ks * KRANGE;

  // pack role: rows prow+32p (p=0..3), cols pcol*8..+8 of each k64 slab
  const int prow = tid >> 3, pcol = tid & 7;
  u16 thu[4];
#pragma unroll
  for (int p = 0; p < 4; ++p) thu[p] = thh[mbase + p * 32 + prow];
  const int* aB = adj + (size_t)(mbase + prow) * NN + k0 + pcol * 8;
  const u16* eB = e1h + k0 + pcol * 8;

  floatx4 acc[2][10];
#pragma unroll
  for (int t = 0; t < 2; ++t)
#pragma unroll
    for (int n = 0; n < 10; ++n) acc[t][n] = (floatx4){0.f, 0.f, 0.f, 0.f};

  intx4 aj[4][2];
  uint4 evv;

  // ---- prologue: DMA slab 0, pack masks for slab 0 into buffer 0 ----
  {
    const char* src = (const char*)(Btf + ((size_t)(k0 >> 5)) * 5120);
#pragma unroll
    for (int i = 0; i < 5; ++i)
      g2l16(src + i * 4096 + tid * 16, (char*)&sB[0][0] + i * 4096 + wave * 1024);
#pragma unroll
    for (int p = 0; p < 4; ++p) {
      aj[p][0] = __builtin_nontemporal_load((const intx4*)(aB + (size_t)p * 32 * NN));
      aj[p][1] = __builtin_nontemporal_load((const intx4*)(aB + (size_t)p * 32 * NN + 4));
    }
    evv = *(const uint4*)eB;
    u32 ev8[8] = {evv.x & 0xFFFFu, evv.x >> 16, evv.y & 0xFFFFu, evv.y >> 16,
                  evv.z & 0xFFFFu, evv.z >> 16, evv.w & 0xFFFFu, evv.w >> 16};
#pragma unroll
    for (int p = 0; p < 4; ++p) {
      const int av[8] = {aj[p][0].x, aj[p][0].y, aj[p][0].z, aj[p][0].w,
                         aj[p][1].x, aj[p][1].y, aj[p][1].z, aj[p][1].w};
      u32 b1 = 0, b2 = 0;
#pragma unroll
      for (int e = 0; e < 8; ++e) {
        const bool nbr = av[e] > 0;
        const bool up = ev8[e] > (u32)thu[p];
        b1 |= (u32)(nbr && up) << e;
        b2 |= (u32)(nbr && !up) << e;
      }
      ((unsigned char*)&m1s[0][p * 32 + prow])[pcol] = (unsigned char)b1;
      ((unsigned char*)&m2s[0][p * 32 + prow])[pcol] = (unsigned char)b2;
    }
  }

  for (int it = 0; it < ITERS; ++it) {
    __syncthreads();                           // slab/masks [cur] ready (drains DMA + LDS)
    const int cur = it & 1, nxt = cur ^ 1;
    const bool more = (it + 1 < ITERS);
    if (more) {                                // stage slab it+1: B via DMA, adj into regs
      const char* src = (const char*)(Btf + ((size_t)(k0 >> 5) + (it + 1) * 2) * 5120);
#pragma unroll
      for (int i = 0; i < 5; ++i)
        g2l16(src + i * 4096 + tid * 16, (char*)&sB[nxt][0] + i * 4096 + wave * 1024);
      const int koff = (it + 1) * 64;
#pragma unroll
      for (int p = 0; p < 4; ++p) {
        aj[p][0] = __builtin_nontemporal_load((const intx4*)(aB + (size_t)p * 32 * NN + koff));
        aj[p][1] = __builtin_nontemporal_load((const intx4*)(aB + (size_t)p * 32 * NN + koff + 4));
      }
      evv = *(const uint4*)(eB + koff);
    }

    // ---- MFMA on [cur] ----
    u64 w1[2], w2[2];
    w1[0] = m1s[cur][wave * 32 + lr];      w1[1] = m1s[cur][wave * 32 + 16 + lr];
    w2[0] = m2s[cur][wave * 32 + lr];      w2[1] = m2s[cur][wave * 32 + 16 + lr];
#pragma unroll
    for (int h = 0; h < 2; ++h) {
      const u32 sh = (u32)(h * 32 + quad * 8);
      union { half8 v; u16 s[8]; } A1[2], A2[2];
      const u32 m1a = (u32)(w1[0] >> sh) & 0xFFu, m2a = (u32)(w2[0] >> sh) & 0xFFu;
      const u32 m1b = (u32)(w1[1] >> sh) & 0xFFu, m2b = (u32)(w2[1] >> sh) & 0xFFu;
#pragma unroll
      for (int e = 0; e < 8; ++e) {
        A1[0].s[e] = ((m1a >> e) & 1u) ? (u16)0x3C00 : (u16)0;
        A2[0].s[e] = ((m2a >> e) & 1u) ? (u16)0x3C00 : (u16)0;
        A1[1].s[e] = ((m1b >> e) & 1u) ? (u16)0x3C00 : (u16)0;
        A2[1].s[e] = ((m2b >> e) & 1u) ? (u16)0x3C00 : (u16)0;
      }
      const u16* bp = &sB[cur][h * 5120];
#pragma unroll
      for (int n = 0; n < 10; ++n) {
        half8 Bv = *(const half8*)(bp + (n * 64 + lane) * 8);
        acc[0][n] = __builtin_amdgcn_mfma_f32_16x16x32_f16(n < 5 ? A1[0].v : A2[0].v, Bv,
                                                           acc[0][n], 0, 0, 0);
        acc[1][n] = __builtin_amdgcn_mfma_f32_16x16x32_f16(n < 5 ? A1[1].v : A2[1].v, Bv,
                                                           acc[1][n], 0, 0, 0);
      }
    }

    // ---- pack masks for slab it+1 into [nxt] ----
    if (more) {
      u32 ev8[8] = {evv.x & 0xFFFFu, evv.x >> 16, evv.y & 0xFFFFu, evv.y >> 16,
                    evv.z & 0xFFFFu, evv.z >> 16, evv.w & 0xFFFFu, evv.w >> 16};
#pragma unroll
      for (int p = 0; p < 4; ++p) {
        const int av[8] = {aj[p][0].x, aj[p][0].y, aj[p][0].z, aj[p][0].w,
                           aj[p][1].x, aj[p][1].y, aj[p][1].z, aj[p][1].w};
        u32 b1 = 0, b2 = 0;
#pragma unroll
        for (int e = 0; e < 8; ++e) {
          const bool nbr = av[e] > 0;
          const bool up = ev8[e] > (u32)thu[p];
          b1 |= (u32)(nbr && up) << e;
          b2 |= (u32)(nbr && !up) << e;
        }
        ((unsigned char*)&m1s[nxt][p * 32 + prow])[pcol] = (unsigned char)b1;
        ((unsigned char*)&m2s[nxt][p * 32 + prow])[pcol] = (unsigned char)b2;
      }
    }
  }

  // partial store. C/D: col=lane&15, row=quad*4+reg; tile t -> local rows wave*32+t*16+..
  const int ks96 = ks * 96 + mpos;
#pragma unroll
  for (int t = 0; t < 2; ++t) {
    float* pp = part + ((size_t)ks96 * 128 + wave * 32 + t * 16 + quad * 4) * 132;
#pragma unroll
    for (int r = 0; r < 4; ++r) {
#pragma unroll
      for (int n = 0; n < 4; ++n)
        pp[r * 132 + n * 16 + lr] = acc[t][n][r];
#pragma unroll
      for (int n = 5; n < 9; ++n)
        pp[r * 132 + 64 + (n - 5) * 16 + lr] = acc[t][n][r];
      if (lr == 0) {
        pp[r * 132 + 128] = acc[t][4][r];      // den+ (group 4, col 0)
        pp[r * 132 + 129] = acc[t][9][r];      // den- (group 9, col 0)
      }
    }
  }
}

// ---------------- K3: reduce 8 k-split partials, scale, divide, ELU ----------------------
__global__ __launch_bounds__(256) void k3_final(
    const float* __restrict__ part, const float* __restrict__ f1g,
    const float* __restrict__ f2g, float* __restrict__ out)
{
  const int gid = blockIdx.x * 256 + threadIdx.x;
  const int row = gid >> 6, col = gid & 63;
  const int mpos = row >> 7, r = row & 127;
  float n1 = 0.f, n2 = 0.f, d1 = 0.f, d2 = 0.f;
#pragma unroll
  for (int ks = 0; ks < KSP; ++ks) {
    const float* p = part + ((size_t)(ks * 96 + mpos) * 128 + r) * 132;
    n1 += p[col]; n2 += p[64 + col]; d1 += p[128]; d2 += p[129];
  }
  const float f1 = f1g[row], f2 = f2g[row];
  const float num = f1 * n1 + f2 * n2;
  const float den = fmaxf(f1 * d1 + f2 * d2, 1e-30f);
  const float x = num / den;
  out[gid] = x > 0.f ? x : (expf(x) - 1.f);
}

extern "C" void kernel_launch(void* const* d_in, const int* in_sizes, int n_in,
                              void* d_out, int out_size, void* d_ws, size_t ws_size,
                              hipStream_t stream) {
  const float* inp = (const float*)d_in[0];
  const int* adj = (const int*)d_in[1];
  const float* W = (const float*)d_in[2];
  const float* a = (const float*)d_in[3];

  // ws: Btf 3,932,160 | part 51,904,512 | e1h 24,576 | thh 24,576 | f1g 49,152 | f2g 49,152
  char* ws = (char*)d_ws;
  u16* Btf = (u16*)ws;
  float* part = (float*)(ws + 3932160);
  char* tail = ws + 3932160 + 51904512;
  u16* e1h = (u16*)tail;
  u16* thh = e1h + NN;
  float* f1g = (float*)(thh + NN);
  float* f2g = f1g + NN;

  k1_prep<<<768, 256, 0, stream>>>(inp, W, a, e1h, thh, f1g, f2g, Btf);
  k2_main<<<768, 256, 0, stream>>>(adj, e1h, thh, Btf, part);
  k3_final<<<NN * OUTF / 256, 256, 0, stream>>>(part, f1g, f2g, (float*)d_out);
}